// Round 3
// baseline (708.417 us; speedup 1.0000x reference)
//
#include <hip/hip_runtime.h>
#include <hip/hip_bf16.h>
#include <math.h>

// Problem constants (from reference setup_inputs)
#define PN    4096
#define PR    4
#define PFIN  256
#define PFOUT 64
#define PALPHA 0.2f
#define INVN  (1.0f/4096.0f)

// ---------------------------------------------------------------------------
// Pass 1: Wh = h @ W  [4096,256]x[256,64]; fused Wh1 = Wh@a[:64], Wh2 = Wh@a[64:]
// grid 256 x 256; block = 16 rows; thread: f = lane, 4 rows. Wave-local dot
// with `a` via butterfly reduction (f == lane, wave == rg group).
__global__ __launch_bounds__(256) void p1_kernel(
    const float* __restrict__ h, const float* __restrict__ W,
    const float* __restrict__ a,
    float* __restrict__ wh, float* __restrict__ wh1, float* __restrict__ wh2)
{
    const int t  = threadIdx.x;
    const int f  = t & 63;
    const int rg = t >> 6;                    // 0..3 == wave id
    const int i0 = blockIdx.x * 16 + rg * 4;  // 4 rows per thread
    const float* h0 = h + (size_t)i0 * PFIN;
    const float av1 = a[f];
    const float av2 = a[64 + f];
    float a0 = 0.f, a1 = 0.f, a2 = 0.f, a3 = 0.f;
#pragma unroll 4
    for (int k = 0; k < PFIN; ++k) {
        const float wv = W[k * PFOUT + f];
        a0 = fmaf(h0[k],            wv, a0);
        a1 = fmaf(h0[PFIN + k],     wv, a1);
        a2 = fmaf(h0[2 * PFIN + k], wv, a2);
        a3 = fmaf(h0[3 * PFIN + k], wv, a3);
    }
    float* o = wh + (size_t)i0 * PFOUT + f;
    o[0]         = a0;
    o[PFOUT]     = a1;
    o[2 * PFOUT] = a2;
    o[3 * PFOUT] = a3;

    // wave butterfly: Wh1/Wh2 for this thread-group's 4 rows
    float s0 = a0 * av1, s1 = a1 * av1, s2 = a2 * av1, s3 = a3 * av1;
    float u0 = a0 * av2, u1 = a1 * av2, u2 = a2 * av2, u3 = a3 * av2;
#pragma unroll
    for (int m = 1; m < 64; m <<= 1) {
        s0 += __shfl_xor(s0, m, 64);
        s1 += __shfl_xor(s1, m, 64);
        s2 += __shfl_xor(s2, m, 64);
        s3 += __shfl_xor(s3, m, 64);
        u0 += __shfl_xor(u0, m, 64);
        u1 += __shfl_xor(u1, m, 64);
        u2 += __shfl_xor(u2, m, 64);
        u3 += __shfl_xor(u3, m, 64);
    }
    if (f == 0) {
        wh1[i0]     = s0; wh1[i0 + 1] = s1; wh1[i0 + 2] = s2; wh1[i0 + 3] = s3;
        wh2[i0]     = u0; wh2[i0 + 1] = u1; wh2[i0 + 2] = u2; wh2[i0 + 3] = u3;
    }
}

// ---------------------------------------------------------------------------
// Pass 2 (per r): x = exp(leaky(wh1[i]+wh2[j])*edge) for edge>0 else 0.
// Writes x (UNNORMALIZED) straight into the e-output region (L3-resident),
// and accumulates column sums (over i) into csum_r via device atomics.
// grid (jt=4, is=128) x 256 thr; thread: 4 consecutive j, 32 rows.
__global__ __launch_bounds__(256) void p2_kernel(
    const float* __restrict__ edge_r, const float* __restrict__ wh1,
    const float* __restrict__ wh2, float* __restrict__ csum_r,
    float* __restrict__ eout_r)
{
    const int t  = threadIdx.x;
    const int jt = blockIdx.x;      // 0..3
    const int is = blockIdx.y;      // 0..127
    const int j  = jt * 1024 + t * 4;
    const int ib = is * 32;
    const float4 w2 = *(const float4*)(wh2 + j);
    const float4* e4 = (const float4*)(edge_r + (size_t)ib * PN + jt * 1024);
    float4*       o4 = (float4*)(eout_r + (size_t)ib * PN + jt * 1024);
    float s0 = 0.f, s1 = 0.f, s2 = 0.f, s3 = 0.f;
#pragma unroll 4
    for (int ii = 0; ii < 32; ++ii) {
        const float w1  = wh1[ib + ii];
        const float4 ev = e4[(size_t)ii * (PN / 4) + t];
        float b0 = w1 + w2.x; b0 = fmaxf(b0, PALPHA * b0);
        float b1 = w1 + w2.y; b1 = fmaxf(b1, PALPHA * b1);
        float b2 = w1 + w2.z; b2 = fmaxf(b2, PALPHA * b2);
        float b3 = w1 + w2.w; b3 = fmaxf(b3, PALPHA * b3);
        const float x0 = (ev.x > 0.f) ? __expf(b0 * ev.x) : 0.f;
        const float x1 = (ev.y > 0.f) ? __expf(b1 * ev.y) : 0.f;
        const float x2 = (ev.z > 0.f) ? __expf(b2 * ev.z) : 0.f;
        const float x3 = (ev.w > 0.f) ? __expf(b3 * ev.w) : 0.f;
        o4[(size_t)ii * (PN / 4) + t] = make_float4(x0, x1, x2, x3);
        s0 += x0; s1 += x1; s2 += x2; s3 += x3;
    }
    atomicAdd(csum_r + j,     s0);
    atomicAdd(csum_r + j + 1, s1);
    atomicAdd(csum_r + j + 2, s2);
    atomicAdd(csum_r + j + 3, s3);
}

// ---------------------------------------------------------------------------
// Pass 3 (per r): normalize-in-place (RMW of L3-hot eout) + streaming GEMM.
// Block = (128-row i-tile, 256-col j-slice), 256 threads, 4 chunks of 64 j.
// Phase A: e *= 1/csum[j] (or INVN for an all-masked column), write back,
// stash XOR-swizzled LDS tile. Phase B: 4x8-register-tile rank-64 update
// vs LDS-staged Wh. Partials: part[js=16][PN][PFOUT] (reused across r).
__global__ __launch_bounds__(256) void p3_kernel(
    float* __restrict__ eout_r, const float* __restrict__ wh,
    const float* __restrict__ csum_r, float* __restrict__ part)
{
    __shared__ float4 ET[64 * 32];  // [jc][rowquad ^ (jc&31)] swizzled, 32 KB
    __shared__ float4 WL[64 * 16];  // [jj][f-quad], 16 KB

    const int t  = threadIdx.x;
    const int it = blockIdx.x;     // 0..31 (128-row i-tiles)
    const int js = blockIdx.y;     // 0..15 (256-col j-slices)
    const int i0 = it * 128;
    const int jc = t & 63;         // phase A: column in chunk
    const int ih = t >> 6;         // 0..3 (wave id)
    const int tf = t & 7;          // phase B: f-octet
    const int tr = t >> 3;         // phase B: row-quad 0..31

    float acc[4][8];
#pragma unroll
    for (int p = 0; p < 4; ++p)
#pragma unroll
        for (int q = 0; q < 8; ++q) acc[p][q] = 0.f;

    const float4* whg4 = (const float4*)wh;

    for (int c = 0; c < 4; ++c) {
        const int j0 = js * 256 + c * 64;
        const int jg = j0 + jc;
        const float cs   = csum_r[jg];
        const float cinv = (cs > 0.f) ? 1.0f / cs : 0.f;

        __syncthreads();  // protect LDS vs previous chunk's GEMM reads

        // stage Wh[j0..j0+63][0..63] -> WL (coalesced float4)
#pragma unroll
        for (int u = 0; u < 4; ++u) {
            const int idx = t + u * 256;
            WL[idx] = whg4[(size_t)j0 * 16 + idx];
        }

        // phase A: each wave handles 8 row-quads for its column jg
#pragma unroll
        for (int k = 0; k < 8; ++k) {
            const int q  = ih * 8 + k;    // row-quad 0..31
            const int il = q * 4;
            float* ep = eout_r + (size_t)(i0 + il) * PN + jg;
            const float e0 = ep[0];
            const float e1 = ep[PN];
            const float e2 = ep[2 * PN];
            const float e3 = ep[3 * PN];
            const float en0 = (cs > 0.f) ? e0 * cinv : INVN;
            const float en1 = (cs > 0.f) ? e1 * cinv : INVN;
            const float en2 = (cs > 0.f) ? e2 * cinv : INVN;
            const float en3 = (cs > 0.f) ? e3 * cinv : INVN;
            ep[0]      = en0;
            ep[PN]     = en1;
            ep[2 * PN] = en2;
            ep[3 * PN] = en3;
            ET[(jc << 5) | (q ^ (jc & 31))] = make_float4(en0, en1, en2, en3);
        }
        __syncthreads();

        // phase B: acc[p][q] += E[i0+tr*4+p][j0+jj] * Wh[j0+jj][tf*8+q]
#pragma unroll 2
        for (int jj = 0; jj < 64; ++jj) {
            const float4 ea = ET[(jj << 5) | (tr ^ (jj & 31))];
            const float4 wa = WL[(jj << 4) | (tf * 2)];
            const float4 wb = WL[(jj << 4) | (tf * 2 + 1)];
            const float ev_[4] = {ea.x, ea.y, ea.z, ea.w};
            const float wv_[8] = {wa.x, wa.y, wa.z, wa.w, wb.x, wb.y, wb.z, wb.w};
#pragma unroll
            for (int p = 0; p < 4; ++p)
#pragma unroll
                for (int q = 0; q < 8; ++q)
                    acc[p][q] = fmaf(ev_[p], wv_[q], acc[p][q]);
        }
    }

    // write partial h' tile: rows i0 + tr*4 + p, cols tf*8..tf*8+7
#pragma unroll
    for (int p = 0; p < 4; ++p) {
        float* pp = part + ((size_t)js * PN + (i0 + tr * 4 + p)) * PFOUT + tf * 8;
        *(float4*)pp       = make_float4(acc[p][0], acc[p][1], acc[p][2], acc[p][3]);
        *(float4*)(pp + 4) = make_float4(acc[p][4], acc[p][5], acc[p][6], acc[p][7]);
    }
}

// ---------------------------------------------------------------------------
// Pass 4 (per r): sum 16 j-slice partials, ELU, write out1 columns r*64..+63.
// grid 256 x 256; thread handles one float4 of one row.
__global__ __launch_bounds__(256) void p4_kernel(
    const float* __restrict__ part, float* __restrict__ out1_r)
{
    const int idx = blockIdx.x * 256 + threadIdx.x;  // 0..65535
    const int i   = idx >> 4;
    const int fq  = idx & 15;
    const float4* pp = (const float4*)part;
    float sx = 0.f, sy = 0.f, sz = 0.f, sw = 0.f;
#pragma unroll
    for (int sj = 0; sj < 16; ++sj) {
        const float4 v = pp[((size_t)sj * PN + i) * 16 + fq];
        sx += v.x; sy += v.y; sz += v.z; sw += v.w;
    }
    float4 o;
    o.x = (sx > 0.f) ? sx : expm1f(sx);
    o.y = (sy > 0.f) ? sy : expm1f(sy);
    o.z = (sz > 0.f) ? sz : expm1f(sz);
    o.w = (sw > 0.f) ? sw : expm1f(sw);
    *(float4*)(out1_r + (size_t)i * (PR * PFOUT) + fq * 4) = o;
}

// ---------------------------------------------------------------------------
extern "C" void kernel_launch(void* const* d_in, const int* in_sizes, int n_in,
                              void* d_out, int out_size, void* d_ws, size_t ws_size,
                              hipStream_t stream)
{
    const float* h    = (const float*)d_in[0];  // [4096][256]
    const float* edge = (const float*)d_in[1];  // [4][4096][4096]
    const float* W    = (const float*)d_in[2];  // [256][64]
    const float* a    = (const float*)d_in[3];  // [128]

    float* out1 = (float*)d_out;                            // [4096][256] elu
    float* eout = (float*)d_out + (size_t)PN * PR * PFOUT;  // [4][4096][4096] e

    // workspace layout (floats); total 4,481,024 floats = 17.9 MB
    float* ws   = (float*)d_ws;
    float* wh   = ws;                 // 262144
    float* wh1  = ws + 262144;        // 4096
    float* wh2  = ws + 266240;        // 4096
    float* csum = ws + 270336;        // 16384
    float* part = ws + 286720;        // 16*4096*64 = 4194304 (reused per r)

    hipMemsetAsync(csum, 0, (size_t)PR * PN * sizeof(float), stream);
    p1_kernel<<<256, 256, 0, stream>>>(h, W, a, wh, wh1, wh2);

    for (int r = 0; r < PR; ++r) {
        float* er_out = eout + (size_t)r * PN * PN;
        p2_kernel<<<dim3(4, 128), 256, 0, stream>>>(
            edge + (size_t)r * PN * PN, wh1, wh2, csum + r * PN, er_out);
        p3_kernel<<<dim3(32, 16), 256, 0, stream>>>(
            er_out, wh, csum + r * PN, part);
        p4_kernel<<<256, 256, 0, stream>>>(part, out1 + r * PFOUT);
    }
}

// Round 4
// 606.324 us; speedup vs baseline: 1.1684x; 1.1684x over previous
//
#include <hip/hip_runtime.h>
#include <hip/hip_bf16.h>
#include <math.h>

// Problem constants (from reference setup_inputs)
#define PN    4096
#define PR    4
#define PFIN  256
#define PFOUT 64
#define PALPHA 0.2f
#define INVN  (1.0f/4096.0f)

// ---------------------------------------------------------------------------
// Pass 1: Wh = h @ W  [4096,256]x[256,64]; fused Wh1 = Wh@a[:64], Wh2 = Wh@a[64:]
// grid 256 x 256; block = 16 rows staged in LDS (coalesced), thread: f = lane,
// 4 rows. Wave-local dot with `a` via butterfly (f == lane).
__global__ __launch_bounds__(256) void p1_kernel(
    const float* __restrict__ h, const float* __restrict__ W,
    const float* __restrict__ a,
    float* __restrict__ wh, float* __restrict__ wh1, float* __restrict__ wh2)
{
    __shared__ float hL[16 * PFIN];  // 16 rows x 256 cols = 16 KB
    const int t  = threadIdx.x;
    const int f  = t & 63;
    const int rg = t >> 6;                    // 0..3 == wave id
    const int i0 = blockIdx.x * 16;
    const int ir = i0 + rg * 4;               // this thread's 4 rows

    // stage h tile (coalesced float4)
    const float4* hg4 = (const float4*)(h + (size_t)i0 * PFIN);
    float4* hL4 = (float4*)hL;
#pragma unroll
    for (int u = 0; u < 4; ++u) hL4[t + 256 * u] = hg4[t + 256 * u];
    __syncthreads();

    const float av1 = a[f];
    const float av2 = a[64 + f];
    const float* h0 = hL + (rg * 4) * PFIN;
    float a0 = 0.f, a1 = 0.f, a2 = 0.f, a3 = 0.f;
#pragma unroll 4
    for (int k = 0; k < PFIN; ++k) {
        const float wv = W[k * PFOUT + f];
        a0 = fmaf(h0[k],            wv, a0);
        a1 = fmaf(h0[PFIN + k],     wv, a1);
        a2 = fmaf(h0[2 * PFIN + k], wv, a2);
        a3 = fmaf(h0[3 * PFIN + k], wv, a3);
    }
    float* o = wh + (size_t)ir * PFOUT + f;
    o[0]         = a0;
    o[PFOUT]     = a1;
    o[2 * PFOUT] = a2;
    o[3 * PFOUT] = a3;

    float s0 = a0 * av1, s1 = a1 * av1, s2 = a2 * av1, s3 = a3 * av1;
    float u0 = a0 * av2, u1 = a1 * av2, u2 = a2 * av2, u3 = a3 * av2;
#pragma unroll
    for (int m = 1; m < 64; m <<= 1) {
        s0 += __shfl_xor(s0, m, 64);
        s1 += __shfl_xor(s1, m, 64);
        s2 += __shfl_xor(s2, m, 64);
        s3 += __shfl_xor(s3, m, 64);
        u0 += __shfl_xor(u0, m, 64);
        u1 += __shfl_xor(u1, m, 64);
        u2 += __shfl_xor(u2, m, 64);
        u3 += __shfl_xor(u3, m, 64);
    }
    if (f == 0) {
        wh1[ir]     = s0; wh1[ir + 1] = s1; wh1[ir + 2] = s2; wh1[ir + 3] = s3;
        wh2[ir]     = u0; wh2[ir + 1] = u1; wh2[ir + 2] = u2; wh2[ir + 3] = u3;
    }
}

// ---------------------------------------------------------------------------
// Pass 2 (all r): stats only. Partial column sums of exp(leaky(wh1[i]+wh2[j])
// *edge) over 64-row slabs -> pcs[r][is][j]. NO atomics, NO e write.
// grid (jt=4, is=64, r=4) x 256 thr; thread owns 4 consecutive j, 64 rows.
__global__ __launch_bounds__(256) void p2s_kernel(
    const float* __restrict__ edge, const float* __restrict__ wh1,
    const float* __restrict__ wh2, float* __restrict__ pcs)
{
    const int t  = threadIdx.x;
    const int jt = blockIdx.x;      // 0..3
    const int is = blockIdx.y;      // 0..63
    const int r  = blockIdx.z;      // 0..3
    const int j  = jt * 1024 + t * 4;
    const int ib = is * 64;
    const float4 w2 = *(const float4*)(wh2 + j);
    const float4* e4 = (const float4*)(edge + ((size_t)r * PN + ib) * PN + jt * 1024);
    float s0 = 0.f, s1 = 0.f, s2 = 0.f, s3 = 0.f;
#pragma unroll 4
    for (int ii = 0; ii < 64; ++ii) {
        const float w1  = wh1[ib + ii];
        const float4 ev = e4[(size_t)ii * (PN / 4) + t];
        float b0 = w1 + w2.x; b0 = fmaxf(b0, PALPHA * b0);
        float b1 = w1 + w2.y; b1 = fmaxf(b1, PALPHA * b1);
        float b2 = w1 + w2.z; b2 = fmaxf(b2, PALPHA * b2);
        float b3 = w1 + w2.w; b3 = fmaxf(b3, PALPHA * b3);
        s0 += (ev.x > 0.f) ? __expf(b0 * ev.x) : 0.f;
        s1 += (ev.y > 0.f) ? __expf(b1 * ev.y) : 0.f;
        s2 += (ev.z > 0.f) ? __expf(b2 * ev.z) : 0.f;
        s3 += (ev.w > 0.f) ? __expf(b3 * ev.w) : 0.f;
    }
    *(float4*)(pcs + ((size_t)r * 64 + is) * PN + j) = make_float4(s0, s1, s2, s3);
}

// ---------------------------------------------------------------------------
// Pass 2b: csum[r][j] = sum over 64 slabs. grid 64 x 256.
__global__ __launch_bounds__(256) void p2b_kernel(
    const float* __restrict__ pcs, float* __restrict__ csum)
{
    const int idx = blockIdx.x * 256 + threadIdx.x;  // 0..16383 = r*4096 + j
    const int r   = idx >> 12;
    const int j   = idx & 4095;
    float s = 0.f;
#pragma unroll
    for (int is = 0; is < 64; ++is)
        s += pcs[((size_t)r * 64 + is) * PN + j];
    csum[idx] = s;
}

// ---------------------------------------------------------------------------
// Pass 3 (all r, dominant): recompute exp, normalize, single e write, fused
// streaming GEMM. Block = (256-row i-tile, 512-col j-slice, r), 256 threads,
// 8 chunks of 64 cols. Phase A: 16 col-quads x 16 row-groups, float4 IO,
// XOR-swizzled ET (write AND read at b128 port floor). Phase B: 8x8 register
// tile (16 FMA per ds_read_b128 -> VALU/LDS balanced, not oversubscribed).
// Partials: part[js=8][r=4][PN][PFOUT].
__global__ __launch_bounds__(256) void p3_kernel(
    const float* __restrict__ edge, const float* __restrict__ wh,
    const float* __restrict__ wh1, const float* __restrict__ wh2,
    const float* __restrict__ csum, float* __restrict__ eout,
    float* __restrict__ part)
{
    __shared__ float4 ET[256 * 16];  // [row][cq ^ ((row>>3)&7)], 64 KB
    __shared__ float4 WL[64 * 16];   // [jj][f-quad], 16 KB

    const int t  = threadIdx.x;
    const int it = blockIdx.x;     // 0..15 (256-row i-tiles)
    const int js = blockIdx.y;     // 0..7  (512-col j-slices)
    const int r  = blockIdx.z;     // 0..3
    const int i0 = it * 256;
    const int cq = t & 15;         // phase A: col-quad 0..15
    const int rg = t >> 4;         // phase A: row-group 0..15
    const int tf = t & 7;          // phase B: f-octet
    const int tr = t >> 3;         // phase B: row-octet 0..31

    float acc[8][8];
#pragma unroll
    for (int p = 0; p < 8; ++p)
#pragma unroll
        for (int q = 0; q < 8; ++q) acc[p][q] = 0.f;

    const float* edge_r = edge + (size_t)r * PN * PN;
    float*       eout_r = eout + (size_t)r * PN * PN;
    const float* csum_r = csum + r * PN;
    const float4* whg4  = (const float4*)wh;

    for (int c = 0; c < 8; ++c) {
        const int j0 = js * 512 + c * 64;
        const int jq = j0 + cq * 4;             // this thread's 4 cols
        const float4 cs4 = *(const float4*)(csum_r + jq);
        const float4 w2  = *(const float4*)(wh2 + jq);
        const float i0x = (cs4.x > 0.f) ? 1.0f / cs4.x : 0.f;
        const float i1x = (cs4.y > 0.f) ? 1.0f / cs4.y : 0.f;
        const float i2x = (cs4.z > 0.f) ? 1.0f / cs4.z : 0.f;
        const float i3x = (cs4.w > 0.f) ? 1.0f / cs4.w : 0.f;
        const float m0 = (cs4.x > 0.f) ? 0.f : INVN;
        const float m1 = (cs4.y > 0.f) ? 0.f : INVN;
        const float m2 = (cs4.z > 0.f) ? 0.f : INVN;
        const float m3 = (cs4.w > 0.f) ? 0.f : INVN;

        __syncthreads();  // previous chunk's phase-B reads done

        // stage W chunk: rows j0..j0+63, 64 f -> 1024 float4
#pragma unroll
        for (int u = 0; u < 4; ++u)
            WL[t + 256 * u] = whg4[(size_t)j0 * 16 + t + 256 * u];

        // phase A: compute e for 256 rows x this thread's 4 cols
#pragma unroll 4
        for (int k = 0; k < 16; ++k) {
            const int row = rg + k * 16;
            const int gi  = i0 + row;
            const float4 ev = *(const float4*)(edge_r + (size_t)gi * PN + jq);
            const float  w1 = wh1[gi];
            float b0 = w1 + w2.x; b0 = fmaxf(b0, PALPHA * b0);
            float b1 = w1 + w2.y; b1 = fmaxf(b1, PALPHA * b1);
            float b2 = w1 + w2.z; b2 = fmaxf(b2, PALPHA * b2);
            float b3 = w1 + w2.w; b3 = fmaxf(b3, PALPHA * b3);
            float4 en;
            en.x = (ev.x > 0.f) ? __expf(b0 * ev.x) * i0x : m0;
            en.y = (ev.y > 0.f) ? __expf(b1 * ev.y) * i1x : m1;
            en.z = (ev.z > 0.f) ? __expf(b2 * ev.z) * i2x : m2;
            en.w = (ev.w > 0.f) ? __expf(b3 * ev.w) * i3x : m3;
            *(float4*)(eout_r + (size_t)gi * PN + jq) = en;
            ET[(row << 4) | (cq ^ ((row >> 3) & 7))] = en;
        }
        __syncthreads();

        // phase B: acc[p][q] += E[i0+tr*8+p][j0+jj] * Wh[j0+jj][tf*8+q]
        for (int jjq = 0; jjq < 16; ++jjq) {
            float4 ev[8];
#pragma unroll
            for (int p = 0; p < 8; ++p) {
                const int row = tr * 8 + p;
                ev[p] = ET[(row << 4) | (jjq ^ (tr & 7))];
            }
#pragma unroll
            for (int u = 0; u < 4; ++u) {
                const int jj = jjq * 4 + u;
                const float4 wa = WL[(jj << 4) | (tf * 2)];
                const float4 wb = WL[(jj << 4) | (tf * 2 + 1)];
#pragma unroll
                for (int p = 0; p < 8; ++p) {
                    const float epv = (u == 0) ? ev[p].x :
                                      (u == 1) ? ev[p].y :
                                      (u == 2) ? ev[p].z : ev[p].w;
                    acc[p][0] = fmaf(epv, wa.x, acc[p][0]);
                    acc[p][1] = fmaf(epv, wa.y, acc[p][1]);
                    acc[p][2] = fmaf(epv, wa.z, acc[p][2]);
                    acc[p][3] = fmaf(epv, wa.w, acc[p][3]);
                    acc[p][4] = fmaf(epv, wb.x, acc[p][4]);
                    acc[p][5] = fmaf(epv, wb.y, acc[p][5]);
                    acc[p][6] = fmaf(epv, wb.z, acc[p][6]);
                    acc[p][7] = fmaf(epv, wb.w, acc[p][7]);
                }
            }
        }
    }

    // write partial h' tile: rows i0 + tr*8 + p, cols tf*8..tf*8+7
#pragma unroll
    for (int p = 0; p < 8; ++p) {
        float* pp = part + (((size_t)js * PR + r) * PN + (i0 + tr * 8 + p)) * PFOUT + tf * 8;
        *(float4*)pp       = make_float4(acc[p][0], acc[p][1], acc[p][2], acc[p][3]);
        *(float4*)(pp + 4) = make_float4(acc[p][4], acc[p][5], acc[p][6], acc[p][7]);
    }
}

// ---------------------------------------------------------------------------
// Pass 4: sum 8 j-slice partials, ELU, write [N][R*FOUT]. grid 1024 x 256.
__global__ __launch_bounds__(256) void p4_kernel(
    const float* __restrict__ part, float* __restrict__ out1)
{
    const int o4 = blockIdx.x * 256 + threadIdx.x;  // float4 index 0..262143
    const int i  = o4 >> 6;
    const int c4 = o4 & 63;
    const int r  = c4 >> 4;
    const int fq = c4 & 15;
    const float4* pp = (const float4*)part;
    float sx = 0.f, sy = 0.f, sz = 0.f, sw = 0.f;
#pragma unroll
    for (int sj = 0; sj < 8; ++sj) {
        const float4 v = pp[(((size_t)sj * PR + r) * PN + i) * 16 + fq];
        sx += v.x; sy += v.y; sz += v.z; sw += v.w;
    }
    float4 o;
    o.x = (sx > 0.f) ? sx : expm1f(sx);
    o.y = (sy > 0.f) ? sy : expm1f(sy);
    o.z = (sz > 0.f) ? sz : expm1f(sz);
    o.w = (sw > 0.f) ? sw : expm1f(sw);
    ((float4*)out1)[o4] = o;
}

// ---------------------------------------------------------------------------
extern "C" void kernel_launch(void* const* d_in, const int* in_sizes, int n_in,
                              void* d_out, int out_size, void* d_ws, size_t ws_size,
                              hipStream_t stream)
{
    const float* h    = (const float*)d_in[0];  // [4096][256]
    const float* edge = (const float*)d_in[1];  // [4][4096][4096]
    const float* W    = (const float*)d_in[2];  // [256][64]
    const float* a    = (const float*)d_in[3];  // [128]

    float* out1 = (float*)d_out;                            // [4096][256] elu
    float* eout = (float*)d_out + (size_t)PN * PR * PFOUT;  // [4][4096][4096] e

    // workspace layout (floats); total ~9.7M floats = 38.8 MB (ws ~820 MB per
    // round-3 poison-fill WRITE_SIZE, so plenty of headroom)
    float* ws   = (float*)d_ws;
    float* wh   = ws;                 // 262144
    float* wh1  = ws + 262144;        // 4096
    float* wh2  = ws + 266240;        // 4096
    float* csum = ws + 270336;        // 16384
    float* pcs  = ws + 286720;        // 4*64*4096 = 1048576
    float* part = ws + 1335296;       // 8*4*4096*64 = 8388608

    p1_kernel <<<256, 256, 0, stream>>>(h, W, a, wh, wh1, wh2);
    p2s_kernel<<<dim3(4, 64, 4), 256, 0, stream>>>(edge, wh1, wh2, pcs);
    p2b_kernel<<<64, 256, 0, stream>>>(pcs, csum);
    p3_kernel <<<dim3(16, 8, 4), 256, 0, stream>>>(edge, wh, wh1, wh2, csum, eout, part);
    p4_kernel <<<1024, 256, 0, stream>>>(part, out1);
}